// Round 9
// baseline (341.254 us; speedup 1.0000x reference)
//
#include <hip/hip_runtime.h>

#define DMODEL 512
#define NHEADS 8
#define DK 64
#define BSZ 4
#define NE 1024
#define NNODE 4096

typedef __attribute__((ext_vector_type(8))) __bf16 bf16x8;
typedef __attribute__((ext_vector_type(4))) float f32x4;
typedef __attribute__((ext_vector_type(8))) unsigned short u16x8;
typedef __attribute__((ext_vector_type(4))) unsigned short u16x4;
typedef __attribute__((ext_vector_type(4))) unsigned int u32x4;

static __device__ __forceinline__ unsigned short f2bf(float f) {
    union { float f; unsigned int u; } v; v.f = f;
    unsigned int u = v.u;
    return (unsigned short)((u + 0x7FFFu + ((u >> 16) & 1u)) >> 16);
}

static __device__ __forceinline__ float bf2f(unsigned short s) {
    union { unsigned int u; float f; } v; v.u = ((unsigned int)s) << 16;
    return v.f;
}

// v_cvt_pk_bf16_f32 (epilogue/conv paths only — NOT in the attn hot loop)
static __device__ __forceinline__ unsigned cvtpk(float lo, float hi) {
    unsigned r;
    asm("v_cvt_pk_bf16_f32 %0, %1, %2" : "=v"(r) : "v"(lo), "v"(hi));
    return r;
}

static __device__ __forceinline__ bf16x8 ldb8(const unsigned short* p) {
    return *reinterpret_cast<const bf16x8*>(p);
}

// async global->LDS DMA, 16B per lane; LDS dest = wave-uniform base + lane*16
static __device__ __forceinline__ void gload16(const unsigned short* g,
                                               unsigned short* l) {
    __builtin_amdgcn_global_load_lds(
        (const __attribute__((address_space(1))) unsigned int*)g,
        (__attribute__((address_space(3))) unsigned int*)l, 16, 0, 0);
}

// ---------------- merged f32 -> bf16 conversion: queries | keys | 4 weights -------
__global__ __launch_bounds__(256) void conv_all(
    const float4* __restrict__ q, const float4* __restrict__ k,
    const float4* __restrict__ wq, const float4* __restrict__ wk,
    const float4* __restrict__ wv, const float4* __restrict__ wo,
    u16x8* __restrict__ qb, u16x8* __restrict__ kb, u16x8* __restrict__ wb) {
    int i = blockIdx.x * 256 + threadIdx.x;
    const float4* s;
    u16x8* d;
    int j;
    if (i < 262144) {
        s = q; d = qb; j = i;
    } else if (i < 1310720) {
        s = k; d = kb; j = i - 262144;
    } else {
        int t = i - 1310720;
        int sel = t >> 15;
        s = sel == 0 ? wq : sel == 1 ? wk : sel == 2 ? wv : wo;
        d = wb + ((size_t)sel << 15);
        j = t & 32767;
    }
    float4 x = s[2 * j];
    float4 y = s[2 * j + 1];
    unsigned u0 = cvtpk(x.x, x.y), u1 = cvtpk(x.z, x.w);
    unsigned u2 = cvtpk(y.x, y.y), u3 = cvtpk(y.z, y.w);
    u16x8 o;
    o[0] = (unsigned short)u0; o[1] = (unsigned short)(u0 >> 16);
    o[2] = (unsigned short)u1; o[3] = (unsigned short)(u1 >> 16);
    o[4] = (unsigned short)u2; o[5] = (unsigned short)(u2 >> 16);
    o[6] = (unsigned short)u3; o[7] = (unsigned short)(u3 >> 16);
    d[j] = o;
}

// ---------------- mask bit-pack: inc int32 (BS*E*N) -> u64 bitgroups ----------------
__global__ __launch_bounds__(256) void maskpack(const int* __restrict__ inc,
                                                unsigned long long* __restrict__ mb) {
    int wid = blockIdx.x * 4 + (threadIdx.x >> 6);
    int lane = threadIdx.x & 63;
#pragma unroll
    for (int j = 0; j < 8; ++j) {
        int g = wid * 8 + j;
        int v = inc[(size_t)g * 64 + lane];
        unsigned long long m = __ballot(v != 0);
        if (lane == 0) mb[g] = m;
    }
}

// ---------------- LDS-staged NT GEMM (m97 structure, 2-phase pipeline) ------------
template <int MODE>
__global__ __launch_bounds__(256) void gemm128(const unsigned short* __restrict__ A,
                                               const unsigned short* __restrict__ W,
                                               const float* __restrict__ bias,
                                               void* __restrict__ Cout, float oscale) {
    int w = threadIdx.x >> 6, l = threadIdx.x & 63;
    int lr = l & 15, lh = l >> 4;
    int wm = w >> 1, wn = w & 1;
    int m0 = blockIdx.x * 128, n0 = blockIdx.y * 128;

    __shared__ unsigned short Ast[2][128][64];
    __shared__ unsigned short Bst[2][128][64];

    int srow = w * 32 + (l >> 3);
    int scu = l & 7;

    auto stage = [&](int bf, int k0) {
#pragma unroll
        for (int ii = 0; ii < 4; ++ii) {
            int row = srow + ii * 8;
            int cu = scu ^ (row & 7);
            gload16(A + (size_t)(m0 + row) * DMODEL + k0 + cu * 8,
                    &Ast[bf][w * 32 + ii * 8][0]);
            gload16(W + (size_t)(n0 + row) * DMODEL + k0 + cu * 8,
                    &Bst[bf][w * 32 + ii * 8][0]);
        }
    };

    f32x4 acc[4][4] = {};

    stage(0, 0);
    __syncthreads();

    int bf = 0;
    for (int t = 0; t < 8; ++t) {
        if (t < 7) stage(bf ^ 1, (t + 1) * 64);
#pragma unroll
        for (int half = 0; half < 2; ++half) {
            bf16x8 af[4], bfr[4];
#pragma unroll
            for (int mf = 0; mf < 4; ++mf)
                af[mf] = ldb8(&Ast[bf][wm * 64 + mf * 16 + lr]
                                  [((half * 4 + lh) ^ (lr & 7)) * 8]);
#pragma unroll
            for (int nf = 0; nf < 4; ++nf)
                bfr[nf] = ldb8(&Bst[bf][wn * 64 + nf * 16 + lr]
                                   [((half * 4 + lh) ^ (lr & 7)) * 8]);
#pragma unroll
            for (int mf = 0; mf < 4; ++mf)
#pragma unroll
                for (int nf = 0; nf < 4; ++nf)
                    acc[mf][nf] = __builtin_amdgcn_mfma_f32_16x16x32_bf16(
                        af[mf], bfr[nf], acc[mf][nf], 0, 0, 0);
        }
        __syncthreads();
        bf ^= 1;
    }

    if constexpr (MODE == 0) {
        unsigned short* C = (unsigned short*)Cout;
#pragma unroll
        for (int nf = 0; nf < 4; ++nf) {
            int ncol = n0 + wn * 64 + nf * 16 + lr;
            float bv = bias[ncol];
#pragma unroll
            for (int mf = 0; mf < 4; ++mf)
#pragma unroll
                for (int r = 0; r < 4; ++r)
                    C[(size_t)(m0 + wm * 64 + mf * 16 + lh * 4 + r) * DMODEL + ncol] =
                        f2bf((acc[mf][nf][r] + bv) * oscale);
        }
    } else if constexpr (MODE == 1) {
        unsigned short* Vt = (unsigned short*)Cout;
        int bb = m0 >> 12;
        int nodebase = (m0 & (NNODE - 1)) + wm * 64;
#pragma unroll
        for (int nf = 0; nf < 4; ++nf) {
            int ncol = n0 + wn * 64 + nf * 16;
            int hh = ncol >> 6;
            int dd = (ncol & 63) + lr;
            float bv = bias[ncol + lr];
#pragma unroll
            for (int mf = 0; mf < 4; ++mf) {
                u16x4 pk;
#pragma unroll
                for (int r = 0; r < 4; ++r) pk[r] = f2bf(acc[mf][nf][r] + bv);
                int node0 = nodebase + mf * 16 + lh * 4;
                *reinterpret_cast<u16x4*>(
                    Vt + (size_t)((bb * NHEADS + hh) * DK + dd) * NNODE + node0) = pk;
            }
        }
    } else {
        float* C = (float*)Cout;
#pragma unroll
        for (int nf = 0; nf < 4; ++nf) {
            int ncol = n0 + wn * 64 + nf * 16 + lr;
            float bv = bias[ncol];
#pragma unroll
            for (int mf = 0; mf < 4; ++mf)
#pragma unroll
                for (int r = 0; r < 4; ++r)
                    C[(size_t)(m0 + wm * 64 + mf * 16 + lh * 4 + r) * DMODEL + ncol] =
                        acc[mf][nf][r] + bv;
        }
    }
}

// ---------------- fused masked attention: node-split waves, swapped QK^T, ---------
// in-register P (k-padded PV). NO inline asm in the hot loop (R8 NaN suspect);
// masks double-buffered in registers so stage-DMA prefetch isn't vmcnt-serialized.
__global__ __launch_bounds__(256) void attn_kernel(
    const unsigned short* __restrict__ Qb, const unsigned short* __restrict__ Kb,
    const unsigned short* __restrict__ Vt, const unsigned long long* __restrict__ mbits,
    unsigned short* __restrict__ Op, float* __restrict__ Lp) {
    int w = threadIdx.x >> 6, l = threadIdx.x & 63;
    int lr = l & 15, lh = l >> 4;
    // id = xcd | (tile<<3) | (ps<<7); pair = xcd*4+ps -> pair's K/V L2-resident per XCD
    int id = blockIdx.x;
    int xcd = id & 7, tile = (id >> 3) & 15, ps = id >> 7;
    int pair = xcd * 4 + ps;
    int b = pair >> 3, h = pair & 7;
    int e0 = tile * 64;

    __shared__ unsigned short Kst[2][64][64];  // [buf][node][dk], XOR-swizzled
    __shared__ unsigned short Vst[2][64][64];  // [buf][d][node], XOR-swizzled

    // Q fragments (B operand), hoisted: qf[et][half]
    bf16x8 qf[4][2];
#pragma unroll
    for (int et = 0; et < 4; ++et) {
        const unsigned short* Qrow =
            Qb + (size_t)(b * NE + e0 + et * 16 + lr) * DMODEL + h * DK;
        qf[et][0] = ldb8(Qrow + lh * 8);
        qf[et][1] = ldb8(Qrow + 32 + lh * 8);
    }

    const unsigned short* Kg = Kb + (size_t)b * NNODE * DMODEL + h * DK;
    const unsigned short* Vg = Vt + (size_t)((b * NHEADS + h) * DK) * NNODE;
    const unsigned long long* mbase = mbits + (size_t)(b * NE + e0) * 64;

    int srow0 = w * 16 + (l >> 3);
    int scol = l & 7;

    auto stage = [&](int sb, int cb) {
#pragma unroll
        for (int ii = 0; ii < 2; ++ii) {
            int row = srow0 + ii * 8;
            int cu = scol ^ (row & 7);
            gload16(Kg + (size_t)(cb * 64 + row) * DMODEL + cu * 8,
                    &Kst[sb][w * 16 + ii * 8][0]);
            gload16(Vg + (size_t)row * NNODE + cb * 64 + cu * 8,
                    &Vst[sb][w * 16 + ii * 8][0]);
        }
    };

    f32x4 oacc[4][4] = {};  // [edge-tile][d-tile]
    float lsum[4] = {0.f, 0.f, 0.f, 0.f};
    int shft = w * 16 + lh * 4;  // this lane's node-bit base within a chunk word

    unsigned long long mcur[4], mnext[4];

    stage(0, 0);
#pragma unroll
    for (int et = 0; et < 4; ++et) mcur[et] = mbase[(size_t)(et * 16 + lr) * 64];
    __syncthreads();

    int bf = 0;
    for (int cb = 0; cb < 64; ++cb) {
        if (cb < 63) {
            stage(bf ^ 1, cb + 1);
#pragma unroll
            for (int et = 0; et < 4; ++et)
                mnext[et] = mbase[(size_t)(et * 16 + lr) * 64 + cb + 1];
        }
        // ---- K A-fragments (swizzled read): rows = wave's 16 nodes ----
        int krow = w * 16 + lr;
        bf16x8 kf0 = ldb8(&Kst[bf][krow][((0 + lh) ^ (lr & 7)) * 8]);
        bf16x8 kf1 = ldb8(&Kst[bf][krow][((4 + lh) ^ (lr & 7)) * 8]);
        // ---- S^T = K Q^T : rows=nodes, cols=edges ----
        f32x4 s[4] = {};
#pragma unroll
        for (int et = 0; et < 4; ++et) {
            s[et] = __builtin_amdgcn_mfma_f32_16x16x32_bf16(kf0, qf[et][0], s[et], 0, 0, 0);
            s[et] = __builtin_amdgcn_mfma_f32_16x16x32_bf16(kf1, qf[et][1], s[et], 0, 0, 0);
        }
        // ---- V B-fragments, k-padded: slots j=0..3 = wave's nodes lh*4+j ----
        u32x4 vf[4];
#pragma unroll
        for (int dt = 0; dt < 4; ++dt) {
            int vrow = dt * 16 + lr;
            int unit = (w * 2 + (lh >> 1)) ^ (lr & 7);
            const unsigned int* p =
                (const unsigned int*)(&Vst[bf][vrow][0] + unit * 8 + (lh & 1) * 4);
            vf[dt][0] = p[0];
            vf[dt][1] = p[1];
            vf[dt][2] = 0u;
            vf[dt][3] = 0u;
        }
        // ---- softmax (fixed shift, exp2 domain, NO inline asm) + in-reg P + PV ----
#pragma unroll
        for (int et = 0; et < 4; ++et) {
            unsigned half32 =
                (shft & 32) ? (unsigned)(mcur[et] >> 32) : (unsigned)mcur[et];
            unsigned mw = (half32 >> (shft & 31)) & 0xFu;
            float p0 = (mw & 1u) ? exp2f(s[et][0]) : 0.0f;
            float p1 = (mw & 2u) ? exp2f(s[et][1]) : 0.0f;
            float p2 = (mw & 4u) ? exp2f(s[et][2]) : 0.0f;
            float p3 = (mw & 8u) ? exp2f(s[et][3]) : 0.0f;
            lsum[et] += (p0 + p1) + (p2 + p3);
            u32x4 af;
            af[0] = ((unsigned)f2bf(p1) << 16) | (unsigned)f2bf(p0);
            af[1] = ((unsigned)f2bf(p3) << 16) | (unsigned)f2bf(p2);
            af[2] = 0u;
            af[3] = 0u;
            bf16x8 a8 = __builtin_bit_cast(bf16x8, af);
#pragma unroll
            for (int dt = 0; dt < 4; ++dt) {
                oacc[et][dt] = __builtin_amdgcn_mfma_f32_16x16x32_bf16(
                    a8, __builtin_bit_cast(bf16x8, vf[dt]), oacc[et][dt], 0, 0, 0);
            }
        }
        __syncthreads();
        bf ^= 1;
#pragma unroll
        for (int et = 0; et < 4; ++et) mcur[et] = mnext[et];
    }

    // ---- lsum: sum the 4 lh node-groups (lanes lr, lr+16, lr+32, lr+48) ----
#pragma unroll
    for (int et = 0; et < 4; ++et) {
        float v = lsum[et];
        v += __shfl_xor(v, 16);
        v += __shfl_xor(v, 32);
        lsum[et] = v;
    }
    // ---- write unnormalized partials: O bf16, L f32 (per wave) ----
    unsigned short* Ow = Op + (size_t)w * ((size_t)BSZ * NE * DMODEL);
#pragma unroll
    for (int et = 0; et < 4; ++et)
#pragma unroll
        for (int dt = 0; dt < 4; ++dt)
#pragma unroll
            for (int r = 0; r < 4; ++r)
                Ow[(size_t)(b * NE + e0 + et * 16 + lh * 4 + r) * DMODEL + h * DK +
                   dt * 16 + lr] = f2bf(oacc[et][dt][r]);
    if (lh == 0) {
        float* Lw = Lp + (size_t)w * ((size_t)BSZ * NHEADS * NE);
#pragma unroll
        for (int et = 0; et < 4; ++et)
            Lw[(size_t)(b * NHEADS + h) * NE + e0 + et * 16 + lr] = lsum[et];
    }
}

// ---------------- combine: Ob = (sum_w Ow) / (sum_w Lw), bf16 ----------------
__global__ __launch_bounds__(256) void combine4(const unsigned short* __restrict__ Op,
                                                const float* __restrict__ Lp,
                                                unsigned short* __restrict__ Ob) {
    int gi = blockIdx.x * 256 + threadIdx.x;  // 0..262143
    size_t base = (size_t)gi * 8;
    int row = (int)(base >> 9);       // b*NE + e
    int h = ((int)base & 511) >> 6;
    int b = row >> 10, e = row & 1023;
    size_t li = (size_t)(b * NHEADS + h) * NE + e;
    const size_t OS = (size_t)BSZ * NE * DMODEL;
    const size_t LS = (size_t)BSZ * NHEADS * NE;
    float L = Lp[li] + Lp[LS + li] + Lp[2 * LS + li] + Lp[3 * LS + li];
    float inv = 1.0f / fmaxf(L, 1e-37f);
    float acc[8] = {};
#pragma unroll
    for (int w2 = 0; w2 < 4; ++w2) {
        u16x8 v = *reinterpret_cast<const u16x8*>(Op + w2 * OS + base);
#pragma unroll
        for (int j = 0; j < 8; ++j) acc[j] += bf2f(v[j]);
    }
    unsigned u0 = cvtpk(acc[0] * inv, acc[1] * inv);
    unsigned u1 = cvtpk(acc[2] * inv, acc[3] * inv);
    unsigned u2 = cvtpk(acc[4] * inv, acc[5] * inv);
    unsigned u3 = cvtpk(acc[6] * inv, acc[7] * inv);
    u16x8 o;
    o[0] = (unsigned short)u0; o[1] = (unsigned short)(u0 >> 16);
    o[2] = (unsigned short)u1; o[3] = (unsigned short)(u1 >> 16);
    o[4] = (unsigned short)u2; o[5] = (unsigned short)(u2 >> 16);
    o[6] = (unsigned short)u3; o[7] = (unsigned short)(u3 >> 16);
    *reinterpret_cast<u16x8*>(Ob + base) = o;
}

// ---------------- launch ----------------
extern "C" void kernel_launch(void* const* d_in, const int* in_sizes, int n_in,
                              void* d_out, int out_size, void* d_ws, size_t ws_size,
                              hipStream_t stream) {
    const float* queries = (const float*)d_in[0];
    const float* keys = (const float*)d_in[1];
    const int* inc = (const int*)d_in[2];
    const float* Wq = (const float*)d_in[3];
    const float* bq = (const float*)d_in[4];
    const float* Wk = (const float*)d_in[5];
    const float* bk = (const float*)d_in[6];
    const float* Wv = (const float*)d_in[7];
    const float* bv = (const float*)d_in[8];
    const float* Wo = (const float*)d_in[9];
    const float* bo = (const float*)d_in[10];

    char* base = (char*)d_ws;
    // [0,2M) mask bits | [2M,4M) weights bf16 | [4M,8M) qbf | [8M,24M) kbf
    // [24,28M) Qb | [28,44M) Kb | [44,60M) Vt | [60,64M) Ob
    // attn partials OVERLAY dead qbf/kbf: Op (bf16) 4x4MB at [4M,20M), Lp [20M,20.5M)
    unsigned long long* mbits = (unsigned long long*)base;
    unsigned short* wqb = (unsigned short*)(base + (2u << 20));
    unsigned short* qbf = (unsigned short*)(base + (4u << 20));
    unsigned short* kbf = (unsigned short*)(base + (8u << 20));
    unsigned short* Qb = (unsigned short*)(base + (24u << 20));
    unsigned short* Kb = (unsigned short*)(base + (28u << 20));
    unsigned short* Vt = (unsigned short*)(base + (44u << 20));
    unsigned short* Ob = (unsigned short*)(base + (60u << 20));
    unsigned short* Opart = (unsigned short*)(base + (4u << 20));
    float* Lpart = (float*)(base + (20u << 20));

    conv_all<<<5632, 256, 0, stream>>>((const float4*)queries, (const float4*)keys,
                                       (const float4*)Wq, (const float4*)Wk,
                                       (const float4*)Wv, (const float4*)Wo,
                                       (u16x8*)qbf, (u16x8*)kbf, (u16x8*)wqb);
    maskpack<<<8192, 256, 0, stream>>>(inc, mbits);

    unsigned short* wkb = wqb + DMODEL * DMODEL;
    unsigned short* wvb = wkb + DMODEL * DMODEL;
    unsigned short* wob = wvb + DMODEL * DMODEL;

    // Q projection pre-scaled by log2(e)/sqrt(d_k) = log2(e)/8 (exp2-domain softmax)
    gemm128<0><<<dim3(BSZ * NE / 128, 4), 256, 0, stream>>>(qbf, wqb, bq, Qb,
                                                            0.18033688f);
    gemm128<0><<<dim3(BSZ * NNODE / 128, 4), 256, 0, stream>>>(kbf, wkb, bk, Kb, 1.0f);
    gemm128<1><<<dim3(BSZ * NNODE / 128, 4), 256, 0, stream>>>(kbf, wvb, bv, Vt, 1.0f);

    attn_kernel<<<dim3(512), 256, 0, stream>>>(Qb, Kb, Vt, mbits, Opart, Lpart);

    combine4<<<dim3(1024), 256, 0, stream>>>(Opart, Lpart, Ob);

    gemm128<2><<<dim3(BSZ * NE / 128, 4), 256, 0, stream>>>(Ob, wob, bo, d_out, 1.0f);
}